// Round 2
// baseline (796.187 us; speedup 1.0000x reference)
//
#include <hip/hip_runtime.h>
#include <hip/hip_bf16.h>
#include <cstdint>
#include <cstddef>

#define HIDDEN   2048
#define EINTER   1024
#define NEXP     8
#define VOCAB_SZ 100000
#define TOK_PER_EXP (VOCAB_SZ / NEXP)   // 12500

typedef unsigned short u16;
typedef __attribute__((ext_vector_type(8))) short short8;   // 8 bf16 in 4 VGPRs
typedef __attribute__((ext_vector_type(4))) float floatx4;  // MFMA C/D

__device__ __forceinline__ int expert_of(int id) {
  id = id < 0 ? 0 : (id > VOCAB_SZ - 1 ? VOCAB_SZ - 1 : id);
  int e = id / TOK_PER_EXP;
  return e > NEXP - 1 ? NEXP - 1 : e;
}

// async global->LDS, 16B per lane. LDS dest = wave-uniform base + lane*16.
__device__ __forceinline__ void gl16(const u16* g, u16* l) {
  __builtin_amdgcn_global_load_lds(
      (const __attribute__((address_space(1))) uint32_t*)g,
      (__attribute__((address_space(3))) uint32_t*)l, 16, 0, 0);
}

// fragment read from XOR-swizzled LDS tile: row stride 64 u16 (128B), chunk = 16B unit.
// storage slot of logical chunk c in row r is c ^ (r & 7)  -> conflict-free b128 reads.
__device__ __forceinline__ short8 ldfrag(const u16* base, int row, int chunk) {
  return *(const short8*)(base + (row << 6) + (((chunk ^ (row & 7))) << 3));
}

// ---------------- routing ----------------
__global__ void count_kernel(const int* __restrict__ tok_ids, int* __restrict__ counts, int T) {
  int t = blockIdx.x * blockDim.x + threadIdx.x;
  if (t < T) atomicAdd(&counts[expert_of(tok_ids[t])], 1);
}

__global__ void scan_kernel(const int* __restrict__ counts, int* __restrict__ offsets,
                            int* __restrict__ cursors) {
  if (threadIdx.x == 0) {
    int s = 0;
    for (int e = 0; e < NEXP; ++e) { offsets[e] = s; cursors[e] = s; s += counts[e]; }
  }
}

__global__ void scatter_kernel(const int* __restrict__ tok_ids, int* __restrict__ cursors,
                               int* __restrict__ tok_list, int T) {
  int t = blockIdx.x * blockDim.x + threadIdx.x;
  if (t < T) {
    int e = expert_of(tok_ids[t]);
    int pos = atomicAdd(&cursors[e], 1);
    tok_list[pos] = t;
  }
}

// ---------------- bf16 pre-pass ----------------
__global__ void gather_x_kernel(const float* __restrict__ x, const int* __restrict__ tok_list,
                                u16* __restrict__ xp) {
  const int row = blockIdx.x;
  const int tok = tok_list[row];
  const float* src = x + (size_t)tok * HIDDEN;
  u16* dst = xp + (size_t)row * HIDDEN;
  const int k = threadIdx.x * 8;
  float4 a = *(const float4*)(src + k);
  float4 b = *(const float4*)(src + k + 4);
  union { uint4 u; u16 s[8]; } pk;
  const float f[8] = {a.x, a.y, a.z, a.w, b.x, b.y, b.z, b.w};
#pragma unroll
  for (int i = 0; i < 8; ++i) {
    __hip_bfloat16 h = __float2bfloat16(f[i]);
    pk.s[i] = *reinterpret_cast<u16*>(&h);
  }
  *(uint4*)(dst + k) = pk.u;
}

// fp32 [R][C] -> bf16 [C][R], 64x64 tiles, 256 thr. Dual-tensor: z<split -> (in0,out0,e=z),
// else (in1,out1,e=z-split). Coalesced float4 reads / uint4 writes.
__global__ void transpose_cvt64(const float* __restrict__ in0, u16* __restrict__ out0,
                                const float* __restrict__ in1, u16* __restrict__ out1,
                                int R, int C, int split) {
  __shared__ float ts[64][65];
  const int z = blockIdx.z;
  const bool first = (z < split) || (in1 == nullptr);
  const float* in = first ? in0 : in1;
  u16* outp = first ? out0 : out1;
  const int e = first ? z : z - split;
  const size_t bo = (size_t)e * R * C;
  const int c0 = blockIdx.x * 64, r0 = blockIdx.y * 64;
  const int lr = threadIdx.x >> 2, lq = threadIdx.x & 3;
#pragma unroll
  for (int j = 0; j < 4; ++j)
    *(float4*)&ts[lr][lq * 16 + j * 4] =
        *(const float4*)&in[bo + (size_t)(r0 + lr) * C + c0 + lq * 16 + j * 4];
  __syncthreads();
#pragma unroll
  for (int j = 0; j < 2; ++j) {
    union { uint4 u; u16 s[8]; } pk;
#pragma unroll
    for (int i = 0; i < 8; ++i) {
      __hip_bfloat16 h = __float2bfloat16(ts[lq * 16 + j * 8 + i][lr]);
      pk.s[i] = *reinterpret_cast<u16*>(&h);
    }
    *(uint4*)&outp[bo + (size_t)(c0 + lr) * R + r0 + lq * 16 + j * 8] = pk.u;
  }
}

// =====================================================================
// 8-phase 256-row GEMM kernels (T2 swizzle + T3/T4 counted vmcnt + T5).
// BM=256, BK=64, 512 thr = 8 waves (2Mx4N), double-buffered 128KiB LDS.
// 4 phases x 16 MFMA per K-tile. Load groups (issue order == gate order):
//   group1 = {A-lo batches (mh=0 rows), B first half}   -> consumed by P1
//   group2 = {B second half}                            -> consumed by P2
//   group3 = {A-hi batches (mh=1 rows)}                 -> consumed by P3
// FIFO ledger (8 outstanding max): prologue vmcnt(4) retires g1(0);
// P1 issues g1(t+1), vmcnt(6) retires g2(t); P2 issues g2(t+1), vmcnt(6)
// retires g3(t); P3 issues g3(t+1), no gate; P4 vmcnt(4) retires g1(t+1).
// vmcnt never drains below 4 in the loop. Last iter re-stages k=0 (dummy,
// branch-free); a single vmcnt(0) after the loop drains before endpgm.
// =====================================================================

// ---- gate/up: A=xp[M][2048], Bg=Gt rows i0..i0+127, Bu=Ut rows i0..i0+127.
// grid (EINTER/128, ceil(T/256), NEXP), 512 thr. silu(g)*u fused epilogue.
__global__ __launch_bounds__(512, 2) void gate_up_8ph(
    const u16* __restrict__ xp, const u16* __restrict__ Gt, const u16* __restrict__ Ut,
    const int* __restrict__ counts, const int* __restrict__ offsets,
    u16* __restrict__ act) {
  __shared__ __align__(16) u16 As[2][256 * 64];
  __shared__ __align__(16) u16 Bg[2][128 * 64];
  __shared__ __align__(16) u16 Bu[2][128 * 64];

  const int e = blockIdx.z;
  const int cnt = counts[e];
  const int row0 = blockIdx.y * 256;
  if (row0 >= cnt) return;
  const int off = offsets[e];
  const int i0 = blockIdx.x * 128;

  const int tid  = threadIdx.x;
  const int lane = tid & 63;
  const int w    = tid >> 6;          // 0..7
  const int wr   = w >> 2;            // 0..1  (M)
  const int wc   = w & 3;             // 0..3  (N)
  const int quad = lane >> 4;
  const int l16  = lane & 15;
  const int lrow   = lane >> 3;
  const int lchunk = (lane & 7) ^ lrow;   // pre-swizzled global source chunk

  // A batches: i=0 -> batch w (rows 0..63 across waves), i=1 -> w+16 (rows 128..191),
  //            i=2 -> w+8 (rows 64..127), i=3 -> w+24 (rows 192..255).
  // group1 stages {i=0,i=1} (mh=0 rows), group3 stages {i=2,i=3} (mh=1 rows).
  const u16* apt[4]; int abase[4];
  {
    const int bsel[4] = {w, w + 16, w + 8, w + 24};
#pragma unroll
    for (int i = 0; i < 4; ++i) {
      int batch = bsel[i];
      int r = batch * 8 + lrow;
      int rg = row0 + r; rg = rg < cnt ? rg : cnt - 1;
      apt[i] = xp + (size_t)(off + rg) * HIDDEN + (lchunk << 3);
      abase[i] = batch << 9;
    }
  }
  const u16 *gpt[2], *upt[2]; int bbase[2];
#pragma unroll
  for (int it = 0; it < 2; ++it) {
    int batch = w + 8 * it;
    int n = batch * 8 + lrow;
    gpt[it] = Gt + ((size_t)e * EINTER + i0 + n) * HIDDEN + (lchunk << 3);
    upt[it] = Ut + ((size_t)e * EINTER + i0 + n) * HIDDEN + (lchunk << 3);
    bbase[it] = batch << 9;
  }

  floatx4 accg[2][4][2], accu[2][4][2];
#pragma unroll
  for (int mh = 0; mh < 2; ++mh)
#pragma unroll
    for (int mf = 0; mf < 4; ++mf)
#pragma unroll
      for (int nf = 0; nf < 2; ++nf) {
        floatx4 z = {0.f, 0.f, 0.f, 0.f};
        accg[mh][mf][nf] = z; accu[mh][mf][nf] = z;
      }

  // prologue: tile 0 into buf 0, issue order g1, g2, g3
  gl16(apt[0], As[0] + abase[0]); gl16(apt[1], As[0] + abase[1]);   // A mh=0
  gl16(gpt[0], Bg[0] + bbase[0]); gl16(gpt[1], Bg[0] + bbase[1]);   // G
  gl16(upt[0], Bu[0] + bbase[0]); gl16(upt[1], Bu[0] + bbase[1]);   // U   (g2)
  gl16(apt[2], As[0] + abase[2]); gl16(apt[3], As[0] + abase[3]);   // A mh=1 (g3)
  asm volatile("s_waitcnt vmcnt(4)" ::: "memory");   // g1(0) done
  __builtin_amdgcn_s_barrier();

  const int NT = HIDDEN / 64;  // 32
  for (int t = 0; t < NT; ++t) {
    const int b  = t & 1;
    const int kn = (t + 1 < NT) ? (t + 1) * 64 : 0;  // last iter: dummy re-stage of k=0
    const u16* Ar = As[b]; const u16* Gr = Bg[b]; const u16* Ur = Bu[b];
    u16* Aw = As[b ^ 1];   u16* Gw = Bg[b ^ 1];   u16* Uw = Bu[b ^ 1];

    short8 af[4][2], bg[2][2], bu[2][2];

    // ---------- P1: (G, mh=0) ----------
#pragma unroll
    for (int mf = 0; mf < 4; ++mf)
#pragma unroll
      for (int s = 0; s < 2; ++s)
        af[mf][s] = ldfrag(Ar, wr * 128 + mf * 16 + l16, s * 4 + quad);
#pragma unroll
    for (int nf = 0; nf < 2; ++nf)
#pragma unroll
      for (int s = 0; s < 2; ++s)
        bg[nf][s] = ldfrag(Gr, wc * 32 + nf * 16 + l16, s * 4 + quad);
    gl16(apt[0] + kn, Aw + abase[0]); gl16(apt[1] + kn, Aw + abase[1]);
    gl16(gpt[0] + kn, Gw + bbase[0]); gl16(gpt[1] + kn, Gw + bbase[1]);
    asm volatile("s_waitcnt vmcnt(6)" ::: "memory");   // g2(t)=U done for P2
    __builtin_amdgcn_s_barrier();
    asm volatile("s_waitcnt lgkmcnt(0)" ::: "memory");
    __builtin_amdgcn_sched_barrier(0);
    __builtin_amdgcn_s_setprio(1);
#pragma unroll
    for (int s = 0; s < 2; ++s)
#pragma unroll
      for (int mf = 0; mf < 4; ++mf)
#pragma unroll
        for (int nf = 0; nf < 2; ++nf)
          accg[0][mf][nf] = __builtin_amdgcn_mfma_f32_16x16x32_bf16(af[mf][s], bg[nf][s], accg[0][mf][nf], 0, 0, 0);
    __builtin_amdgcn_s_setprio(0);
    __builtin_amdgcn_sched_barrier(0);
    __builtin_amdgcn_s_barrier();

    // ---------- P2: (U, mh=0) ----------
#pragma unroll
    for (int nf = 0; nf < 2; ++nf)
#pragma unroll
      for (int s = 0; s < 2; ++s)
        bu[nf][s] = ldfrag(Ur, wc * 32 + nf * 16 + l16, s * 4 + quad);
    gl16(upt[0] + kn, Uw + bbase[0]); gl16(upt[1] + kn, Uw + bbase[1]);
    asm volatile("s_waitcnt vmcnt(6)" ::: "memory");   // g3(t)=A-hi done for P3
    __builtin_amdgcn_s_barrier();
    asm volatile("s_waitcnt lgkmcnt(0)" ::: "memory");
    __builtin_amdgcn_sched_barrier(0);
    __builtin_amdgcn_s_setprio(1);
#pragma unroll
    for (int s = 0; s < 2; ++s)
#pragma unroll
      for (int mf = 0; mf < 4; ++mf)
#pragma unroll
        for (int nf = 0; nf < 2; ++nf)
          accu[0][mf][nf] = __builtin_amdgcn_mfma_f32_16x16x32_bf16(af[mf][s], bu[nf][s], accu[0][mf][nf], 0, 0, 0);
    __builtin_amdgcn_s_setprio(0);
    __builtin_amdgcn_sched_barrier(0);
    __builtin_amdgcn_s_barrier();

    // ---------- P3: (G, mh=1) ----------
#pragma unroll
    for (int mf = 0; mf < 4; ++mf)
#pragma unroll
      for (int s = 0; s < 2; ++s)
        af[mf][s] = ldfrag(Ar, wr * 128 + 64 + mf * 16 + l16, s * 4 + quad);
    gl16(apt[2] + kn, Aw + abase[2]); gl16(apt[3] + kn, Aw + abase[3]);
    __builtin_amdgcn_s_barrier();
    asm volatile("s_waitcnt lgkmcnt(0)" ::: "memory");
    __builtin_amdgcn_sched_barrier(0);
    __builtin_amdgcn_s_setprio(1);
#pragma unroll
    for (int s = 0; s < 2; ++s)
#pragma unroll
      for (int mf = 0; mf < 4; ++mf)
#pragma unroll
        for (int nf = 0; nf < 2; ++nf)
          accg[1][mf][nf] = __builtin_amdgcn_mfma_f32_16x16x32_bf16(af[mf][s], bg[nf][s], accg[1][mf][nf], 0, 0, 0);
    __builtin_amdgcn_s_setprio(0);
    __builtin_amdgcn_sched_barrier(0);
    __builtin_amdgcn_s_barrier();

    // ---------- P4: (U, mh=1) ----------
    asm volatile("s_waitcnt vmcnt(4)" ::: "memory");   // g1(t+1) done for next P1
    __builtin_amdgcn_s_barrier();
    __builtin_amdgcn_s_setprio(1);
#pragma unroll
    for (int s = 0; s < 2; ++s)
#pragma unroll
      for (int mf = 0; mf < 4; ++mf)
#pragma unroll
        for (int nf = 0; nf < 2; ++nf)
          accu[1][mf][nf] = __builtin_amdgcn_mfma_f32_16x16x32_bf16(af[mf][s], bu[nf][s], accu[1][mf][nf], 0, 0, 0);
    __builtin_amdgcn_s_setprio(0);
    __builtin_amdgcn_sched_barrier(0);
    __builtin_amdgcn_s_barrier();
  }
  asm volatile("s_waitcnt vmcnt(0)" ::: "memory");   // drain dummy stages before endpgm

  // epilogue: C/D layout col=l16, row=quad*4+reg. silu(g)*u -> bf16 act
#pragma unroll
  for (int mh = 0; mh < 2; ++mh)
#pragma unroll
    for (int mf = 0; mf < 4; ++mf)
#pragma unroll
      for (int nf = 0; nf < 2; ++nf)
#pragma unroll
        for (int rg = 0; rg < 4; ++rg) {
          int r = wr * 128 + mh * 64 + mf * 16 + quad * 4 + rg;
          if (row0 + r < cnt) {
            float g = accg[mh][mf][nf][rg];
            float u = accu[mh][mf][nf][rg];
            float y = (g / (1.f + __expf(-g))) * u;
            __hip_bfloat16 h = __float2bfloat16(y);
            act[((size_t)(off + row0 + r)) * EINTER + i0 + wc * 32 + nf * 16 + l16] =
                *reinterpret_cast<u16*>(&h);
          }
        }
}

// ---- down: A=act[M][1024], B=Dt rows j0..j0+255 (nh=0: first 128, nh=1: second).
// grid (HIDDEN/256, ceil(T/256), NEXP), 512 thr. fp32 scatter rows to out.
__global__ __launch_bounds__(512, 2) void down_8ph(
    const u16* __restrict__ act, const u16* __restrict__ Dt,
    const int* __restrict__ counts, const int* __restrict__ offsets,
    const int* __restrict__ tok_list, float* __restrict__ out) {
  __shared__ __align__(16) u16 As[2][256 * 64];
  __shared__ __align__(16) u16 Bs[2][256 * 64];
  __shared__ int toks[256];

  const int e = blockIdx.z;
  const int cnt = counts[e];
  const int row0 = blockIdx.y * 256;
  if (row0 >= cnt) return;
  const int off = offsets[e];
  const int j0 = blockIdx.x * 256;

  const int tid  = threadIdx.x;
  const int lane = tid & 63;
  const int w    = tid >> 6;
  const int wr   = w >> 2;
  const int wc   = w & 3;
  const int quad = lane >> 4;
  const int l16  = lane & 15;
  const int lrow   = lane >> 3;
  const int lchunk = (lane & 7) ^ lrow;

  if (tid < 256) {
    int r = row0 + tid;
    toks[tid] = tok_list[off + (r < cnt ? r : cnt - 1)];
  }

  const u16* apt[4]; int abase[4];
  {
    const int bsel[4] = {w, w + 16, w + 8, w + 24};   // g1: {0,1}, g3: {2,3}
#pragma unroll
    for (int i = 0; i < 4; ++i) {
      int batch = bsel[i];
      int r = batch * 8 + lrow;
      int rg = row0 + r; rg = rg < cnt ? rg : cnt - 1;
      apt[i] = act + (size_t)(off + rg) * EINTER + (lchunk << 3);
      abase[i] = batch << 9;
    }
  }
  const u16* dpt[4]; int dbase[4];
#pragma unroll
  for (int i = 0; i < 4; ++i) {       // batches w, w+8 (nh=0); w+16, w+24 (nh=1)
    int batch = w + 8 * i;
    int n = j0 + batch * 8 + lrow;
    dpt[i] = Dt + ((size_t)e * HIDDEN + n) * EINTER + (lchunk << 3);
    dbase[i] = batch << 9;
  }

  floatx4 acc[2][2][4][2];   // [mh][nh][mf][nf']
#pragma unroll
  for (int mh = 0; mh < 2; ++mh)
#pragma unroll
    for (int nh = 0; nh < 2; ++nh)
#pragma unroll
      for (int mf = 0; mf < 4; ++mf)
#pragma unroll
        for (int nf = 0; nf < 2; ++nf) {
          floatx4 z = {0.f, 0.f, 0.f, 0.f};
          acc[mh][nh][mf][nf] = z;
        }

  // prologue, issue order g1={a0,a1,d0,d1}, g2={d2,d3}, g3={a2,a3}
  asm volatile("s_waitcnt lgkmcnt(0)" ::: "memory");   // toks ds_write visible pre-barrier
  gl16(apt[0], As[0] + abase[0]); gl16(apt[1], As[0] + abase[1]);
  gl16(dpt[0], Bs[0] + dbase[0]); gl16(dpt[1], Bs[0] + dbase[1]);
  gl16(dpt[2], Bs[0] + dbase[2]); gl16(dpt[3], Bs[0] + dbase[3]);
  gl16(apt[2], As[0] + abase[2]); gl16(apt[3], As[0] + abase[3]);
  asm volatile("s_waitcnt vmcnt(4)" ::: "memory");
  __builtin_amdgcn_s_barrier();

  const int NT = EINTER / 64;  // 16
  for (int t = 0; t < NT; ++t) {
    const int b  = t & 1;
    const int kn = (t + 1 < NT) ? (t + 1) * 64 : 0;
    const u16* Ar = As[b]; const u16* Br = Bs[b];
    u16* Aw = As[b ^ 1];   u16* Bw = Bs[b ^ 1];

    short8 af[4][2], b0[2][2], b1[2][2];

    // ---------- P1: (mh=0, nh=0) ----------
#pragma unroll
    for (int mf = 0; mf < 4; ++mf)
#pragma unroll
      for (int s = 0; s < 2; ++s)
        af[mf][s] = ldfrag(Ar, wr * 128 + mf * 16 + l16, s * 4 + quad);
#pragma unroll
    for (int nf = 0; nf < 2; ++nf)
#pragma unroll
      for (int s = 0; s < 2; ++s)
        b0[nf][s] = ldfrag(Br, wc * 32 + nf * 16 + l16, s * 4 + quad);
    gl16(apt[0] + kn, Aw + abase[0]); gl16(apt[1] + kn, Aw + abase[1]);
    gl16(dpt[0] + kn, Bw + dbase[0]); gl16(dpt[1] + kn, Bw + dbase[1]);
    asm volatile("s_waitcnt vmcnt(6)" ::: "memory");   // g2(t) done for P2
    __builtin_amdgcn_s_barrier();
    asm volatile("s_waitcnt lgkmcnt(0)" ::: "memory");
    __builtin_amdgcn_sched_barrier(0);
    __builtin_amdgcn_s_setprio(1);
#pragma unroll
    for (int s = 0; s < 2; ++s)
#pragma unroll
      for (int mf = 0; mf < 4; ++mf)
#pragma unroll
        for (int nf = 0; nf < 2; ++nf)
          acc[0][0][mf][nf] = __builtin_amdgcn_mfma_f32_16x16x32_bf16(af[mf][s], b0[nf][s], acc[0][0][mf][nf], 0, 0, 0);
    __builtin_amdgcn_s_setprio(0);
    __builtin_amdgcn_sched_barrier(0);
    __builtin_amdgcn_s_barrier();

    // ---------- P2: (mh=0, nh=1) ----------
#pragma unroll
    for (int nf = 0; nf < 2; ++nf)
#pragma unroll
      for (int s = 0; s < 2; ++s)
        b1[nf][s] = ldfrag(Br, 128 + wc * 32 + nf * 16 + l16, s * 4 + quad);
    gl16(dpt[2] + kn, Bw + dbase[2]); gl16(dpt[3] + kn, Bw + dbase[3]);
    asm volatile("s_waitcnt vmcnt(6)" ::: "memory");   // g3(t) done for P3
    __builtin_amdgcn_s_barrier();
    asm volatile("s_waitcnt lgkmcnt(0)" ::: "memory");
    __builtin_amdgcn_sched_barrier(0);
    __builtin_amdgcn_s_setprio(1);
#pragma unroll
    for (int s = 0; s < 2; ++s)
#pragma unroll
      for (int mf = 0; mf < 4; ++mf)
#pragma unroll
        for (int nf = 0; nf < 2; ++nf)
          acc[0][1][mf][nf] = __builtin_amdgcn_mfma_f32_16x16x32_bf16(af[mf][s], b1[nf][s], acc[0][1][mf][nf], 0, 0, 0);
    __builtin_amdgcn_s_setprio(0);
    __builtin_amdgcn_sched_barrier(0);
    __builtin_amdgcn_s_barrier();

    // ---------- P3: (mh=1, nh=0) ----------
#pragma unroll
    for (int mf = 0; mf < 4; ++mf)
#pragma unroll
      for (int s = 0; s < 2; ++s)
        af[mf][s] = ldfrag(Ar, wr * 128 + 64 + mf * 16 + l16, s * 4 + quad);
    gl16(apt[2] + kn, Aw + abase[2]); gl16(apt[3] + kn, Aw + abase[3]);
    __builtin_amdgcn_s_barrier();
    asm volatile("s_waitcnt lgkmcnt(0)" ::: "memory");
    __builtin_amdgcn_sched_barrier(0);
    __builtin_amdgcn_s_setprio(1);
#pragma unroll
    for (int s = 0; s < 2; ++s)
#pragma unroll
      for (int mf = 0; mf < 4; ++mf)
#pragma unroll
        for (int nf = 0; nf < 2; ++nf)
          acc[1][0][mf][nf] = __builtin_amdgcn_mfma_f32_16x16x32_bf16(af[mf][s], b0[nf][s], acc[1][0][mf][nf], 0, 0, 0);
    __builtin_amdgcn_s_setprio(0);
    __builtin_amdgcn_sched_barrier(0);
    __builtin_amdgcn_s_barrier();

    // ---------- P4: (mh=1, nh=1) ----------
    asm volatile("s_waitcnt vmcnt(4)" ::: "memory");   // g1(t+1) done for next P1
    __builtin_amdgcn_s_barrier();
    __builtin_amdgcn_s_setprio(1);
#pragma unroll
    for (int s = 0; s < 2; ++s)
#pragma unroll
      for (int mf = 0; mf < 4; ++mf)
#pragma unroll
        for (int nf = 0; nf < 2; ++nf)
          acc[1][1][mf][nf] = __builtin_amdgcn_mfma_f32_16x16x32_bf16(af[mf][s], b1[nf][s], acc[1][1][mf][nf], 0, 0, 0);
    __builtin_amdgcn_s_setprio(0);
    __builtin_amdgcn_sched_barrier(0);
    __builtin_amdgcn_s_barrier();
  }
  asm volatile("s_waitcnt vmcnt(0)" ::: "memory");   // drain dummy stages before endpgm

#pragma unroll
  for (int mh = 0; mh < 2; ++mh)
#pragma unroll
    for (int nh = 0; nh < 2; ++nh)
#pragma unroll
      for (int mf = 0; mf < 4; ++mf)
#pragma unroll
        for (int nf = 0; nf < 2; ++nf)
#pragma unroll
          for (int rg = 0; rg < 4; ++rg) {
            int r = wr * 128 + mh * 64 + mf * 16 + quad * 4 + rg;
            if (row0 + r < cnt)
              out[(size_t)toks[r] * HIDDEN + j0 + nh * 128 + wc * 32 + nf * 16 + l16] =
                  acc[mh][nh][mf][nf][rg];
          }
}

// ---------------- fp32 fallback (round-1, known-correct; used only if ws too small) ----
#define TM 64
#define TN 64
#define TK 16

__global__ __launch_bounds__(256, 2) void gate_up_fp32(
    const float* __restrict__ x, const float* __restrict__ G, const float* __restrict__ U,
    const int* __restrict__ counts, const int* __restrict__ offsets,
    const int* __restrict__ tok_list, float* __restrict__ act) {
  __shared__ __align__(16) float Xs[TK][TM + 4];
  __shared__ __align__(16) float Gs[TK][TN];
  __shared__ __align__(16) float Us[TK][TN];
  __shared__ int toks[TM];
  const int e = blockIdx.z, cnt = counts[e], row0 = blockIdx.y * TM;
  if (row0 >= cnt) return;
  const int off = offsets[e], i0 = blockIdx.x * TN, tid = threadIdx.x;
  if (tid < TM) { int r = row0 + tid; toks[tid] = tok_list[off + (r < cnt ? r : 0)]; }
  __syncthreads();
  const float* Ge = G + (size_t)e * HIDDEN * EINTER + i0;
  const float* Ue = U + (size_t)e * HIDDEN * EINTER + i0;
  const int kk_ld = tid & 15, r_ld = tid >> 4, i_ld = tid & 63, k_ld = tid >> 6;
  const int tx = tid & 15, ty = tid >> 4;
  float ag[4][4] = {{0.f}}, au[4][4] = {{0.f}};
  for (int k0 = 0; k0 < HIDDEN; k0 += TK) {
#pragma unroll
    for (int rr = 0; rr < 4; ++rr) {
      int r = r_ld + rr * 16;
      Xs[kk_ld][r] = x[(size_t)toks[r] * HIDDEN + k0 + kk_ld];
    }
#pragma unroll
    for (int kk = 0; kk < 4; ++kk) {
      int k = k_ld + kk * 4;
      Gs[k][i_ld] = Ge[(size_t)(k0 + k) * EINTER + i_ld];
      Us[k][i_ld] = Ue[(size_t)(k0 + k) * EINTER + i_ld];
    }
    __syncthreads();
#pragma unroll
    for (int kk = 0; kk < TK; ++kk) {
      float4 a = *(const float4*)&Xs[kk][ty * 4];
      float4 bg = *(const float4*)&Gs[kk][tx * 4];
      float4 bu = *(const float4*)&Us[kk][tx * 4];
      const float av[4] = {a.x, a.y, a.z, a.w}, bgv[4] = {bg.x, bg.y, bg.z, bg.w},
                  buv[4] = {bu.x, bu.y, bu.z, bu.w};
#pragma unroll
      for (int i = 0; i < 4; ++i)
#pragma unroll
        for (int j = 0; j < 4; ++j) {
          ag[i][j] = fmaf(av[i], bgv[j], ag[i][j]);
          au[i][j] = fmaf(av[i], buv[j], au[i][j]);
        }
    }
    __syncthreads();
  }
#pragma unroll
  for (int i = 0; i < 4; ++i) {
    int r = row0 + ty * 4 + i;
    if (r < cnt) {
      float4 o; float* op = (float*)&o;
#pragma unroll
      for (int j = 0; j < 4; ++j) {
        float g = ag[i][j], u = au[i][j];
        op[j] = (g / (1.0f + expf(-g))) * u;
      }
      *(float4*)&act[(size_t)(off + r) * EINTER + i0 + tx * 4] = o;
    }
  }
}

__global__ __launch_bounds__(256, 2) void down_fp32(
    const float* __restrict__ act, const float* __restrict__ D,
    const int* __restrict__ counts, const int* __restrict__ offsets,
    const int* __restrict__ tok_list, float* __restrict__ out) {
  __shared__ __align__(16) float As[TK][TM + 4];
  __shared__ __align__(16) float Ds[TK][TN];
  __shared__ int toks[TM];
  const int e = blockIdx.z, cnt = counts[e], row0 = blockIdx.y * TM;
  if (row0 >= cnt) return;
  const int off = offsets[e], j0 = blockIdx.x * TN, tid = threadIdx.x;
  if (tid < TM) { int r = row0 + tid; toks[tid] = tok_list[off + (r < cnt ? r : 0)]; }
  const float* De = D + (size_t)e * EINTER * HIDDEN + j0;
  const int kk_ld = tid & 15, r_ld = tid >> 4, i_ld = tid & 63, k_ld = tid >> 6;
  const int tx = tid & 15, ty = tid >> 4;
  float acc[4][4] = {{0.f}};
  for (int k0 = 0; k0 < EINTER; k0 += TK) {
#pragma unroll
    for (int rr = 0; rr < 4; ++rr) {
      int r = r_ld + rr * 16;
      int grow = row0 + r;
      As[kk_ld][r] = act[(size_t)(off + (grow < cnt ? grow : 0)) * EINTER + k0 + kk_ld];
    }
#pragma unroll
    for (int kk = 0; kk < 4; ++kk) {
      int k = k_ld + kk * 4;
      Ds[k][i_ld] = De[(size_t)(k0 + k) * HIDDEN + i_ld];
    }
    __syncthreads();
#pragma unroll
    for (int kk = 0; kk < TK; ++kk) {
      float4 a = *(const float4*)&As[kk][ty * 4];
      float4 b = *(const float4*)&Ds[kk][tx * 4];
      const float av[4] = {a.x, a.y, a.z, a.w}, bv[4] = {b.x, b.y, b.z, b.w};
#pragma unroll
      for (int i = 0; i < 4; ++i)
#pragma unroll
        for (int j = 0; j < 4; ++j)
          acc[i][j] = fmaf(av[i], bv[j], acc[i][j]);
    }
    __syncthreads();
  }
#pragma unroll
  for (int i = 0; i < 4; ++i) {
    int r = row0 + ty * 4 + i;
    if (r < cnt) {
      float4 o = {acc[i][0], acc[i][1], acc[i][2], acc[i][3]};
      *(float4*)&out[(size_t)toks[ty * 4 + i] * HIDDEN + j0 + tx * 4] = o;
    }
  }
}

// ---------------- launch ----------------
extern "C" void kernel_launch(void* const* d_in, const int* in_sizes, int n_in,
                              void* d_out, int out_size, void* d_ws, size_t ws_size,
                              hipStream_t stream) {
  const float* x       = (const float*)d_in[0];
  const int*   tok_ids = (const int*)d_in[1];
  const float* G       = (const float*)d_in[2];
  const float* U       = (const float*)d_in[3];
  const float* D       = (const float*)d_in[4];
  float* out = (float*)d_out;

  const int T = in_sizes[0] / HIDDEN;  // 16384

  int* counts   = (int*)d_ws;
  int* offsets  = counts + NEXP;
  int* cursors  = offsets + NEXP;
  int* tok_list = cursors + NEXP;
  size_t hdr_bytes = (((size_t)(3 * NEXP + T) * sizeof(int)) + 255) & ~(size_t)255;

  hipMemsetAsync(counts, 0, NEXP * sizeof(int), stream);
  count_kernel<<<(T + 255) / 256, 256, 0, stream>>>(tok_ids, counts, T);
  scan_kernel<<<1, 64, 0, stream>>>(counts, offsets, cursors);
  scatter_kernel<<<(T + 255) / 256, 256, 0, stream>>>(tok_ids, cursors, tok_list, T);

  const size_t xp_bytes  = (size_t)T * HIDDEN * 2;
  const size_t w_bytes   = (size_t)NEXP * HIDDEN * EINTER * 2;
  const size_t act_bf16  = (size_t)T * EINTER * 2;
  const size_t need_bf16 = hdr_bytes + xp_bytes + 3 * w_bytes + act_bf16;

  if (ws_size >= need_bf16) {
    char* p = (char*)d_ws + hdr_bytes;
    u16* xp = (u16*)p;   p += xp_bytes;
    u16* Gt = (u16*)p;   p += w_bytes;
    u16* Ut = (u16*)p;   p += w_bytes;
    u16* Dt = (u16*)p;   p += w_bytes;
    u16* act = (u16*)p;

    gather_x_kernel<<<T, 256, 0, stream>>>(x, tok_list, xp);
    // G,U: [2048][1024] -> [1024][2048] (fused, z=16); D: [1024][2048] -> [2048][1024]
    transpose_cvt64<<<dim3(EINTER / 64, HIDDEN / 64, 2 * NEXP), 256, 0, stream>>>(
        G, Gt, U, Ut, HIDDEN, EINTER, NEXP);
    transpose_cvt64<<<dim3(HIDDEN / 64, EINTER / 64, NEXP), 256, 0, stream>>>(
        D, Dt, nullptr, nullptr, EINTER, HIDDEN, NEXP);

    dim3 g1(EINTER / 128, (T + 255) / 256, NEXP);
    gate_up_8ph<<<g1, 512, 0, stream>>>(xp, Gt, Ut, counts, offsets, act);
    dim3 g2(HIDDEN / 256, (T + 255) / 256, NEXP);
    down_8ph<<<g2, 512, 0, stream>>>(act, Dt, counts, offsets, tok_list, out);
  } else {
    float* act = (float*)((char*)d_ws + hdr_bytes);
    dim3 g1(EINTER / TN, (T + TM - 1) / TM, NEXP);
    gate_up_fp32<<<g1, 256, 0, stream>>>(x, G, U, counts, offsets, tok_list, act);
    dim3 g2(HIDDEN / TN, (T + TM - 1) / TM, NEXP);
    down_fp32<<<g2, 256, 0, stream>>>(act, D, counts, offsets, tok_list, out);
  }
}